// Round 1
// 1326.175 us; speedup vs baseline: 1.3428x; 1.3428x over previous
//
#include <hip/hip_runtime.h>

#define Nn 4096
#define Dd 512
#define Ee 65536
#define HOPS 10
#define TPB 512
#define RPT (Nn / TPB)  // 8 rows per thread
#define CT 4            // columns per block
#define WCAP 64         // ELL slot capacity (max in-degree+1; Poisson(16) max ~38)

// ---------------- sq[i] = sum_d w_d * x[i,d]^2 ----------------
__global__ __launch_bounds__(256) void k_sq(const float* __restrict__ x,
                                            const float* __restrict__ w,
                                            float* __restrict__ sq) {
  int row = blockIdx.x;
  int tid = threadIdx.x;
  const float* xr = x + (size_t)row * Dd;
  float partial = 0.f;
  for (int d = tid; d < Dd; d += 256) {
    float xv = xr[d];
    partial += xv * xv * w[d];
  }
  for (int off = 32; off >= 1; off >>= 1) partial += __shfl_down(partial, off, 64);
  __shared__ float red[4];
  int wv = tid >> 6, ln = tid & 63;
  if (ln == 0) red[wv] = partial;
  __syncthreads();
  if (tid == 0) sq[row] = red[0] + red[1] + red[2] + red[3];
}

// ---------------- K = sq_i + sq_j - 2 * (x*w) @ x^T ; diag -> 1 ----------------
__global__ __launch_bounds__(256) void k_gemm(const float* __restrict__ X,
                                              const float* __restrict__ w,
                                              const float* __restrict__ sq,
                                              float* __restrict__ C) {
  __shared__ float As[8][128];
  __shared__ float Bs[8][128];
  int i0 = blockIdx.y * 128, j0 = blockIdx.x * 128;
  int tid = threadIdx.x;
  int ty = tid >> 4, tx = tid & 15;
  int lr = tid >> 1, lk = (tid & 1) * 4;
  float acc[8][8];
#pragma unroll
  for (int a = 0; a < 8; a++)
#pragma unroll
    for (int b = 0; b < 8; b++) acc[a][b] = 0.f;

  for (int k0 = 0; k0 < Dd; k0 += 8) {
    float4 wv4 = *(const float4*)&w[k0 + lk];
    float4 av4 = *(const float4*)&X[(size_t)(i0 + lr) * Dd + k0 + lk];
    float4 bv4 = *(const float4*)&X[(size_t)(j0 + lr) * Dd + k0 + lk];
    As[lk + 0][lr] = av4.x * wv4.x; As[lk + 1][lr] = av4.y * wv4.y;
    As[lk + 2][lr] = av4.z * wv4.z; As[lk + 3][lr] = av4.w * wv4.w;
    Bs[lk + 0][lr] = bv4.x; Bs[lk + 1][lr] = bv4.y; Bs[lk + 2][lr] = bv4.z; Bs[lk + 3][lr] = bv4.w;
    __syncthreads();
#pragma unroll
    for (int kk = 0; kk < 8; kk++) {
      float av[8], bv[8];
      *(float4*)&av[0] = *(const float4*)&As[kk][ty * 8];
      *(float4*)&av[4] = *(const float4*)&As[kk][ty * 8 + 4];
      *(float4*)&bv[0] = *(const float4*)&Bs[kk][tx * 8];
      *(float4*)&bv[4] = *(const float4*)&Bs[kk][tx * 8 + 4];
#pragma unroll
      for (int a = 0; a < 8; a++)
#pragma unroll
        for (int b = 0; b < 8; b++) acc[a][b] += av[a] * bv[b];
    }
    __syncthreads();
  }
#pragma unroll
  for (int a = 0; a < 8; a++) {
    int gi = i0 + ty * 8 + a;
    float sqi = sq[gi];
    float outv[8];
#pragma unroll
    for (int b = 0; b < 8; b++) {
      int gj = j0 + tx * 8 + b;
      float v = sqi + sq[gj] - 2.f * acc[a][b];
      outv[b] = (gi == gj) ? 1.0f : v;
    }
    float* Cr = &C[(size_t)gi * Nn + j0 + tx * 8];
    *(float4*)&Cr[0] = *(float4*)&outv[0];
    *(float4*)&Cr[4] = *(float4*)&outv[4];
  }
}

// ---------------- degree counting ----------------
__global__ void k_count(const int* __restrict__ src, const int* __restrict__ dst,
                        int* __restrict__ degi, int* __restrict__ degrow) {
  int e = blockIdx.x * blockDim.x + threadIdx.x;
  if (e < Ee) {
    atomicAdd(&degi[dst[e]], 1);
    atomicAdd(&degrow[src[e]], 1);
  }
}

// ---------------- dis = (deg_in+1)^-0.5 ----------------
__global__ void k_dis(const int* __restrict__ degi, float* __restrict__ dis) {
  int i = blockIdx.x * 256 + threadIdx.x;
  dis[i] = rsqrtf((float)(degi[i] + 1));
}

// ---------------- histogram of (deg_in+1) + exclusive prefix -> binbase ----------------
__global__ void k_hist(const int* __restrict__ degi, int* __restrict__ binbase) {
  __shared__ int h[WCAP + 1];
  int t = threadIdx.x;
  if (t <= WCAP) h[t] = 0;
  __syncthreads();
  for (int i = t; i < Nn; i += 256) {
    int d = degi[i] + 1;
    if (d > WCAP) d = WCAP;
    atomicAdd(&h[d], 1);
  }
  __syncthreads();
  if (t == 0) {
    int run = 0;
    for (int b = 0; b <= WCAP; b++) { int c = h[b]; binbase[b] = run; run += c; }
  }
}

// ---------------- counting-sort scatter: perm (sorted pos -> row), rnk (row -> pos) ----------------
__global__ void k_scatter(const int* __restrict__ degi, const int* __restrict__ binbase,
                          int* __restrict__ bincnt, int* __restrict__ perm,
                          int* __restrict__ rnk) {
  int i = blockIdx.x * 256 + threadIdx.x;
  int d = degi[i] + 1;
  if (d > WCAP) d = WCAP;
  int pos = binbase[d] + atomicAdd(&bincnt[d], 1);
  perm[pos] = i;
  rnk[i] = pos;
}

// ---------------- per-(wave,chain) slot bounds: max degree in each 64-row sorted sub-chunk ----------------
__global__ void k_wsub(const int* __restrict__ degi, const int* __restrict__ perm,
                       int* __restrict__ wsub) {
  int t = threadIdx.x;  // 64 threads, one per sub-chunk
  int d = degi[perm[t * 64 + 63]] + 1;  // ascending sort -> max at end of sub-chunk
  wsub[t] = d > WCAP ? WCAP : d;
}

// ---------------- ELL fill (slot-major, sorted-position indexed) ----------------
// ell[slot*Nn + rnk[dstrow]] = {srccol, norm}; pre-zeroed dummies = {0, 0.0f}.
__global__ void k_fill_ell(const int* __restrict__ src, const int* __restrict__ dst,
                           const float* __restrict__ dis, const int* __restrict__ rnk,
                           int* __restrict__ slot, int2* __restrict__ ell) {
  int i = blockIdx.x * blockDim.x + threadIdx.x;
  if (i < Ee) {
    int s = src[i], d = dst[i];
    int p = atomicAdd(&slot[d], 1);
    if (p < WCAP) ell[(size_t)p * Nn + rnk[d]] = make_int2(s, __float_as_int(dis[s] * dis[d]));
  } else if (i < Ee + Nn) {
    int v = i - Ee;
    int p = atomicAdd(&slot[v], 1);
    if (p < WCAP) ell[(size_t)p * Nn + rnk[v]] = make_int2(v, __float_as_int(dis[v] * dis[v]));
  }
}

// ---------------- fused 10-hop APPNP on a 4-column slab; h resident in LDS ----------------
// Rows degree-sorted: wave wv owns sorted positions [wv*512, wv*512+512), chain rr the
// 64-row sub-chunk [wv*512+rr*64, +64). Each sub-chunk loops only to its own max degree
// ws[rr] (wave-uniform scalar branch) -> ~2.2x fewer LDS gathers + ELL loads vs global-max
// ELL. Staging & writeback stay tid-linear (coalesced) by routing results through h4.
template <int PASS>
__global__ __launch_bounds__(TPB, 4) void k_appnp(const float* __restrict__ xsrc,
                                                  float* __restrict__ dstp,
                                                  const int2* __restrict__ ell,
                                                  const int* __restrict__ perm,
                                                  const int* __restrict__ wsub,
                                                  const int* __restrict__ degrow) {
  extern __shared__ float4 h4[];  // Nn entries = 64 KB
  int j0 = blockIdx.x * CT;
  int tid = threadIdx.x;
  int wv = tid >> 6, ln = tid & 63;
  int qb = wv * 512 + ln;  // sorted-position base for this thread's chains

  // stage x0 slab into LDS, coalesced, original row order
#pragma unroll
  for (int rr = 0; rr < RPT; rr++) {
    int r = tid + rr * TPB;
    float4 v;
    v.x = xsrc[(size_t)(j0 + 0) * Nn + r];
    v.y = xsrc[(size_t)(j0 + 1) * Nn + r];
    v.z = xsrc[(size_t)(j0 + 2) * Nn + r];
    v.w = xsrc[(size_t)(j0 + 3) * Nn + r];
    h4[r] = v;
  }

  int ws[RPT];
#pragma unroll
  for (int rr = 0; rr < RPT; rr++)
    ws[rr] = __builtin_amdgcn_readfirstlane(wsub[wv * 8 + rr]);  // wave-uniform -> SGPR
  const int Wv = ws[RPT - 1];  // ascending within chunk -> last is the wave max

  int rp[RPT];
#pragma unroll
  for (int rr = 0; rr < RPT; rr++) rp[rr] = perm[qb + rr * 64];

  __syncthreads();
  float4 x0r[RPT];
#pragma unroll
  for (int rr = 0; rr < RPT; rr++) x0r[rr] = h4[rp[rr]];

  float4 acc[RPT];
  for (int it = 0; it < HOPS; it++) {
    int2 cur[RPT];
#pragma unroll
    for (int rr = 0; rr < RPT; rr++) cur[rr] = ell[qb + rr * 64];  // slot 0 always exists
#pragma unroll
    for (int rr = 0; rr < RPT; rr++) acc[rr] = x0r[rr];  // alpha*x0 folded: res = 0.5*(x0+sum)
    for (int s = 0; s < Wv; s++) {
      int sn = s + 1;
      int2 nxt[RPT];
#pragma unroll
      for (int rr = 0; rr < RPT; rr++)
        if (sn < ws[rr]) nxt[rr] = ell[(size_t)sn * Nn + qb + rr * 64];
#pragma unroll
      for (int rr = 0; rr < RPT; rr++)
        if (s < ws[rr]) {
          float vv = __int_as_float(cur[rr].y);
          float4 hu = h4[cur[rr].x];
          acc[rr].x = fmaf(vv, hu.x, acc[rr].x);
          acc[rr].y = fmaf(vv, hu.y, acc[rr].y);
          acc[rr].z = fmaf(vv, hu.z, acc[rr].z);
          acc[rr].w = fmaf(vv, hu.w, acc[rr].w);
        }
#pragma unroll
      for (int rr = 0; rr < RPT; rr++)
        if (sn < ws[rr]) cur[rr] = nxt[rr];
    }
#pragma unroll
    for (int rr = 0; rr < RPT; rr++) {
      acc[rr].x *= 0.5f; acc[rr].y *= 0.5f; acc[rr].z *= 0.5f; acc[rr].w *= 0.5f;
    }
    __syncthreads();
#pragma unroll
    for (int rr = 0; rr < RPT; rr++) h4[rp[rr]] = acc[rr];  // scattered, bijective
    __syncthreads();
  }

  // writeback from h4, tid-linear (same global pattern as before)
  if (PASS == 1) {
#pragma unroll
    for (int rr = 0; rr < RPT; rr++) {
      int r = tid + rr * TPB;
      *(float4*)&dstp[(size_t)r * Nn + j0] = h4[r];
    }
  } else {
#pragma unroll
    for (int rr = 0; rr < RPT; rr++) {
      int r = tid + rr * TPB;
      float4 a = h4[r];
      float vals[4] = {a.x, a.y, a.z, a.w};
#pragma unroll
      for (int c = 0; c < 4; c++) {
        float v = vals[c];
        if (r == j0 + c) v *= 1.0f / ((float)degrow[r] + 1.0f);
        dstp[(size_t)(j0 + c) * Nn + r] = v;
      }
    }
  }
}

extern "C" void kernel_launch(void* const* d_in, const int* in_sizes, int n_in,
                              void* d_out, int out_size, void* d_ws, size_t ws_size,
                              hipStream_t stream) {
  const float* x = (const float*)d_in[0];  // [N,D]
  const float* w = (const float*)d_in[1];  // [D]
  const int* ei = (const int*)d_in[2];     // [2,E]
  const int* src = ei;
  const int* dstv = ei + Ee;
  float* out = (float*)d_out;

  // workspace layout (~69 MB)
  float* W1 = (float*)d_ws;                     // Nn*Nn : K
  float* sq = W1 + (size_t)Nn * Nn;             // Nn
  float* dis = sq + Nn;                         // Nn
  int2* ell = (int2*)(dis + Nn);                // WCAP*Nn (2 MB)
  int* degi = (int*)(ell + (size_t)WCAP * Nn);  // Nn
  int* degrow = degi + Nn;                      // Nn
  int* slotcnt = degrow + Nn;                   // Nn
  int* bincnt = slotcnt + Nn;                   // WCAP+1
  int* binbase = bincnt + (WCAP + 1);           // WCAP+1
  int* perm = binbase + (WCAP + 1);             // Nn
  int* rnk = perm + Nn;                         // Nn
  int* wsub = rnk + Nn;                         // 64

  hipMemsetAsync(ell, 0, (size_t)WCAP * Nn * sizeof(int2), stream);
  hipMemsetAsync(degi, 0, sizeof(int) * (3 * Nn + (WCAP + 1)), stream);  // degi,degrow,slotcnt,bincnt

  k_sq<<<Nn, 256, 0, stream>>>(x, w, sq);
  k_gemm<<<dim3(Nn / 128, Nn / 128), 256, 0, stream>>>(x, w, sq, W1);
  k_count<<<Ee / 256, 256, 0, stream>>>(src, dstv, degi, degrow);
  k_dis<<<Nn / 256, 256, 0, stream>>>(degi, dis);
  k_hist<<<1, 256, 0, stream>>>(degi, binbase);
  k_scatter<<<Nn / 256, 256, 0, stream>>>(degi, binbase, bincnt, perm, rnk);
  k_wsub<<<1, 64, 0, stream>>>(degi, perm, wsub);
  k_fill_ell<<<(Ee + Nn + 255) / 256, 256, 0, stream>>>(src, dstv, dis, rnk, slotcnt, ell);

  // pass 1: kgg1 = APPNP(K) -> out (row-major)
  k_appnp<1><<<Nn / CT, TPB, Nn * sizeof(float4), stream>>>(W1, out, ell, perm, wsub, nullptr);
  // pass 2: in-place on out: reads kgg1 rows, writes final (kgg2^T, diag-scaled)
  k_appnp<2><<<Nn / CT, TPB, Nn * sizeof(float4), stream>>>(out, out, ell, perm, wsub, degrow);
}